// Round 8
// baseline (270.299 us; speedup 1.0000x reference)
//
#include <hip/hip_runtime.h>

#define DIN 128
#define DHID 128
#define DOUT 64

__device__ __forceinline__ float bf2f(ushort u) {
  return __uint_as_float(((unsigned)u) << 16);
}
__device__ __forceinline__ ushort f2bf(float f) {  // round-to-nearest-even
  unsigned u = __float_as_uint(f);
  return (ushort)((u + 0x7fffu + ((u >> 16) & 1u)) >> 16);
}

// ---------------- CSR build ----------------

__global__ void k_init(int* counts, int* cursor, int n) {
  int i = blockIdx.x * blockDim.x + threadIdx.x;
  if (i < n) { counts[i] = 0; cursor[i] = 0; }
}

__global__ void k_hist(const int* __restrict__ ei, int E, int* __restrict__ counts) {
  int e = blockIdx.x * blockDim.x + threadIdx.x;
  if (e < E) atomicAdd(&counts[__builtin_nontemporal_load(ei + E + e)], 1);
}

__global__ void k_dinv(const int* __restrict__ counts, float* __restrict__ dinv, int n) {
  int i = blockIdx.x * blockDim.x + threadIdx.x;
  if (i < n) dinv[i] = 1.0f / sqrtf((float)(counts[i] + 1));  // +1 self loop
}

__global__ __launch_bounds__(1024) void k_scan1(const int* __restrict__ counts,
                                                int* __restrict__ rowptr,
                                                int* __restrict__ bsums, int n) {
  __shared__ int s[1024];
  int tid = threadIdx.x;
  int idx = blockIdx.x * 1024 + tid;
  int v = (idx < n) ? counts[idx] : 0;
  s[tid] = v;
  __syncthreads();
  for (int off = 1; off < 1024; off <<= 1) {
    int t = (tid >= off) ? s[tid - off] : 0;
    __syncthreads();
    s[tid] += t;
    __syncthreads();
  }
  if (idx < n) rowptr[idx] = s[tid] - v;   // exclusive within block
  if (tid == 1023) bsums[blockIdx.x] = s[1023];
}

__global__ void k_scan2(int* bsums, int nb) {
  // one wave, nb <= 64 (N <= 65536). exclusive scan of block sums.
  int l = threadIdx.x;
  if (nb <= 64) {
    int v = (l < nb) ? bsums[l] : 0;
    int orig = v;
    for (int off = 1; off < 64; off <<= 1) {
      int t = __shfl_up(v, off);
      if (l >= off) v += t;
    }
    if (l < nb) bsums[l] = v - orig;
  } else if (l == 0) {
    int run = 0;
    for (int b = 0; b < nb; ++b) { int v = bsums[b]; bsums[b] = run; run += v; }
  }
}

__global__ __launch_bounds__(1024) void k_scan3(int* __restrict__ rowptr,
                                                const int* __restrict__ bsums, int n, int E) {
  int idx = blockIdx.x * 1024 + threadIdx.x;
  if (idx < n) rowptr[idx] += bsums[blockIdx.x];
  if (idx == 0) rowptr[n] = E;
}

__global__ void k_scatter(const int* __restrict__ ei, int E,
                          const int* __restrict__ rowptr, int* __restrict__ cursor,
                          int* __restrict__ csrc) {
  int e = blockIdx.x * blockDim.x + threadIdx.x;
  if (e >= E) return;
  int s = __builtin_nontemporal_load(ei + e);
  int d = __builtin_nontemporal_load(ei + E + e);
  int pos = rowptr[d] + atomicAdd(&cursor[d], 1);
  csrc[pos] = s;
}

// ---------------- tiny weight GEMMs ----------------

template <int NCOL>
__global__ void k_mmnaive(const float* __restrict__ A, const float* __restrict__ B,
                          float* __restrict__ C) {
  int t = blockIdx.x * blockDim.x + threadIdx.x;
  if (t >= 128 * NCOL) return;
  int i = t / NCOL, j = t % NCOL;
  float s = 0.f;
  for (int k = 0; k < 128; ++k) s = fmaf(A[i * 128 + k], B[k * NCOL + j], s);
  C[t] = s;
}

__global__ void k_cvec(const float* __restrict__ b1, const float* __restrict__ b2,
                       const float* __restrict__ b3, const float* __restrict__ W2,
                       const float* __restrict__ W3, float* __restrict__ c1,
                       float* __restrict__ c2, float* __restrict__ c3) {
  __shared__ float t1[DHID];
  int j = threadIdx.x;
  float s = 0.f;
  for (int k = 0; k < DHID; ++k) s = fmaf(b1[k], W2[k * DHID + j], s);
  t1[j] = s;
  __syncthreads();
  if (j < DOUT) {
    float a = 0.f, b = 0.f;
    for (int k = 0; k < DHID; ++k) {
      a = fmaf(t1[k], W3[k * DOUT + j], a);
      b = fmaf(b2[k], W3[k * DOUT + j], b);
    }
    c1[j] = a; c2[j] = b; c3[j] = b3[j];
  }
}

// ---------------- P0 = dinv * (X @ Wc), bf16, slice-major [64/W][N][W] ----------------

__global__ __launch_bounds__(256) void k_xw(const float* __restrict__ X,
                                            const float* __restrict__ Wc,
                                            const float* __restrict__ dinv,
                                            ushort* __restrict__ Hs, int n, int W) {
  __shared__ float Xs[64][68];
  __shared__ float Ws[64][64];
  int t = threadIdx.x;
  int br = blockIdx.x * 64;
  int r4 = t >> 4, c4 = t & 15;
  float4 acc[4];
#pragma unroll
  for (int i = 0; i < 4; ++i) acc[i] = make_float4(0.f, 0.f, 0.f, 0.f);

  for (int chunk = 0; chunk < 2; ++chunk) {
    int k0 = chunk * 64;
    __syncthreads();
#pragma unroll
    for (int j = 0; j < 4; ++j) {
      int f4 = t + j * 256;
      int row = f4 >> 4, col4 = f4 & 15;
      int gr = br + row;
      float4 v = make_float4(0.f, 0.f, 0.f, 0.f);
      if (gr < n) v = *(const float4*)&X[(size_t)gr * DIN + k0 + col4 * 4];
      *(float4*)&Xs[row][col4 * 4] = v;
      float4 w = *(const float4*)&Wc[(size_t)(k0 + row) * DOUT + col4 * 4];
      *(float4*)&Ws[row][col4 * 4] = w;
    }
    __syncthreads();
#pragma unroll
    for (int kk = 0; kk < 16; ++kk) {
      float4 xv[4], wv[4];
#pragma unroll
      for (int i = 0; i < 4; ++i) xv[i] = *(const float4*)&Xs[r4 * 4 + i][kk * 4];
#pragma unroll
      for (int q = 0; q < 4; ++q) wv[q] = *(const float4*)&Ws[kk * 4 + q][c4 * 4];
#pragma unroll
      for (int i = 0; i < 4; ++i) {
        acc[i].x = fmaf(xv[i].x, wv[0].x, acc[i].x);
        acc[i].y = fmaf(xv[i].x, wv[0].y, acc[i].y);
        acc[i].z = fmaf(xv[i].x, wv[0].z, acc[i].z);
        acc[i].w = fmaf(xv[i].x, wv[0].w, acc[i].w);
        acc[i].x = fmaf(xv[i].y, wv[1].x, acc[i].x);
        acc[i].y = fmaf(xv[i].y, wv[1].y, acc[i].y);
        acc[i].z = fmaf(xv[i].y, wv[1].z, acc[i].z);
        acc[i].w = fmaf(xv[i].y, wv[1].w, acc[i].w);
        acc[i].x = fmaf(xv[i].z, wv[2].x, acc[i].x);
        acc[i].y = fmaf(xv[i].z, wv[2].y, acc[i].y);
        acc[i].z = fmaf(xv[i].z, wv[2].z, acc[i].z);
        acc[i].w = fmaf(xv[i].z, wv[2].w, acc[i].w);
        acc[i].x = fmaf(xv[i].w, wv[3].x, acc[i].x);
        acc[i].y = fmaf(xv[i].w, wv[3].y, acc[i].y);
        acc[i].z = fmaf(xv[i].w, wv[3].z, acc[i].z);
        acc[i].w = fmaf(xv[i].w, wv[3].w, acc[i].w);
      }
    }
  }
#pragma unroll
  for (int i = 0; i < 4; ++i) {
    int gr = br + r4 * 4 + i;
    if (gr < n) {
      float dv = dinv[gr];
      int col = c4 * 4;                // 4-col group lies within one slice (W % 4 == 0)
      int p = col / W, off = col - p * W;
      ushort4 hv;
      hv.x = f2bf(acc[i].x * dv); hv.y = f2bf(acc[i].y * dv);
      hv.z = f2bf(acc[i].z * dv); hv.w = f2bf(acc[i].w * dv);
      *(ushort4*)&Hs[((size_t)p * n + gr) * W + off] = hv;
    }
  }
}

// ---------------- aggregation round on a feature slice ----------------
// ONE NODE PER WAVE: 64 lanes = (64/W) edge sub-groups x W features.
// Sub-group s handles edges beg+s, beg+s+nsub, ... (lockstep, no divergence).
// Cross-sub combine via shfl_xor over the sub bits.
// input P (= dinv * H, bf16). T[v] = P[v] + sum_{s in in(v)} P[s].
// rounds 1,2 write Pnext = dinv^2 * T (bf16); round 3 writes di*T + rank-1 bias.

template <int ROUND>
__global__ __launch_bounds__(256) void k_agg(const ushort* __restrict__ in,
                                             ushort* __restrict__ out16,
                                             float* __restrict__ out32,
                                             const int* __restrict__ rowptr,
                                             const int* __restrict__ csrc,
                                             const float* __restrict__ dinv,
                                             float* __restrict__ r1t, float* __restrict__ r1s,
                                             float* __restrict__ r2t,
                                             const float* __restrict__ c1,
                                             const float* __restrict__ c2,
                                             const float* __restrict__ c3,
                                             int n, int W, int wsh, int c0, int pass0) {
  int id = blockIdx.x * blockDim.x + threadIdx.x;
  int node = id >> 6;                         // one 64-lane wave per node
  if (node >= n) return;
  int lane = threadIdx.x & 63;
  int feat = lane & (W - 1);
  int sub  = lane >> wsh;                     // edge sub-group
  int nsub = 64 >> wsh;
  int beg = rowptr[node], end = rowptr[node + 1];
  float di = dinv[node];
  float a0 = 0.f, a1 = 0.f, a2 = 0.f, a3 = 0.f, racc = 0.f;
  bool doR = (ROUND != 3) && pass0;
  int e = beg + sub;
  int step = nsub;
  for (; e + 3 * step < end; e += 4 * step) {   // 4 per sub-group in flight
    int s0 = __builtin_nontemporal_load(csrc + e);
    int s1 = __builtin_nontemporal_load(csrc + e + step);
    int s2 = __builtin_nontemporal_load(csrc + e + 2 * step);
    int s3 = __builtin_nontemporal_load(csrc + e + 3 * step);
    float h0 = bf2f(in[(size_t)s0 * W + feat]);
    float h1 = bf2f(in[(size_t)s1 * W + feat]);
    float h2 = bf2f(in[(size_t)s2 * W + feat]);
    float h3 = bf2f(in[(size_t)s3 * W + feat]);
    a0 += h0; a1 += h1; a2 += h2; a3 += h3;
    if (doR) {
      if (ROUND == 1) racc += (dinv[s0] + dinv[s1]) + (dinv[s2] + dinv[s3]);
      if (ROUND == 2) racc += (r1s[s0] + r1s[s1]) + (r1s[s2] + r1s[s3]);
    }
  }
  for (; e < end; e += step) {
    int s = __builtin_nontemporal_load(csrc + e);
    a0 += bf2f(in[(size_t)s * W + feat]);
    if (doR) {
      if (ROUND == 1) racc += dinv[s];
      if (ROUND == 2) racc += r1s[s];
    }
  }
  float acc = (a0 + a1) + (a2 + a3);
  // combine edge sub-groups (lanes with same feat, different sub)
  for (int off = W; off < 64; off <<= 1) {
    acc += __shfl_xor(acc, off);
    if (doR) racc += __shfl_xor(racc, off);
  }
  float T = acc + bf2f(in[(size_t)node * W + feat]);   // + self P[v]
  float d2 = di * di;
  if (ROUND == 1 && doR) {
    racc += di;                          // self p0 = dinv_v
    if (lane == 0) { r1t[node] = di * racc; r1s[node] = d2 * racc; }
  }
  if (ROUND == 2 && doR) {
    racc += r1s[node];                   // self term
    if (lane == 0) r2t[node] = di * racc;
  }
  if (sub == 0) {
    if (ROUND == 3) {
      int cf = c0 + feat;
      float v = fmaf(r1t[node], c2[cf], c3[cf]);
      v = fmaf(r2t[node], c1[cf], v);
      out32[(size_t)node * DOUT + cf] = fmaf(di, T, v);
    } else {
      out16[(size_t)node * W + feat] = f2bf(d2 * T);
    }
  }
}

// ---------------- launch ----------------

extern "C" void kernel_launch(void* const* d_in, const int* in_sizes, int n_in,
                              void* d_out, int out_size, void* d_ws, size_t ws_size,
                              hipStream_t stream) {
  const float* X  = (const float*)d_in[0];
  const int*   ei = (const int*)d_in[1];
  const float* W1 = (const float*)d_in[2];
  const float* b1 = (const float*)d_in[3];
  const float* W2 = (const float*)d_in[4];
  const float* b2 = (const float*)d_in[5];
  const float* W3 = (const float*)d_in[6];
  const float* b3 = (const float*)d_in[7];
  const int N = in_sizes[0] / DIN;
  const int E = in_sizes[1] / 2;
  float* out = (float*)d_out;

  auto AL = [](size_t x) -> size_t { return (x + 255) & ~(size_t)255; };

  // slice width 32 (2 passes): per-pass gather working set N*W*2 = 3.2 MB < 4 MiB L2.
  size_t fixedBytes = AL((size_t)(N + 1) * 4) + AL(256 * 4) + AL((size_t)N * 4) * 4
                    + AL((size_t)E * 4) + AL((size_t)DIN * DHID * 4)
                    + AL((size_t)DIN * DOUT * 4) + 3 * AL(DOUT * 4);
  int W = 32;
  while (W > 8 && fixedBytes + AL((size_t)N * DOUT * 2) + AL((size_t)N * W * 2) > ws_size)
    W >>= 1;
  const int SLICES = DOUT / W;
  int wsh = 0; while ((1 << wsh) < W) ++wsh;

  char* p = (char*)d_ws;
  auto alloc = [&](size_t nbytes) -> void* {
    void* r = (void*)p;
    p += AL(nbytes);
    return r;
  };
  int*    rowptr = (int*)alloc((size_t)(N + 1) * 4);
  int*    bsums  = (int*)alloc(256 * 4);
  float*  dinv   = (float*)alloc((size_t)N * 4);
  int*    csrc   = (int*)alloc((size_t)E * 4);
  int*    counts = (int*)alloc((size_t)N * 4);   // aliased -> r1t
  int*    cursor = (int*)alloc((size_t)N * 4);   // aliased -> r1s
  float*  r2t    = (float*)alloc((size_t)N * 4);
  float*  wtmp   = (float*)alloc((size_t)DIN * DHID * 4);
  float*  wc     = (float*)alloc((size_t)DIN * DOUT * 4);
  float*  c1     = (float*)alloc(DOUT * 4);
  float*  c2     = (float*)alloc(DOUT * 4);
  float*  c3     = (float*)alloc(DOUT * 4);
  ushort* Hfull  = (ushort*)alloc((size_t)N * DOUT * 2);  // slice-major [SLICES][N][W]
  ushort* S1     = (ushort*)alloc((size_t)N * W * 2);
  float*  r1t    = (float*)counts;
  float*  r1s    = (float*)cursor;

  // ---- CSR build (once) ----
  k_init<<<(N + 255) / 256, 256, 0, stream>>>(counts, cursor, N);
  k_hist<<<(E + 255) / 256, 256, 0, stream>>>(ei, E, counts);
  k_dinv<<<(N + 255) / 256, 256, 0, stream>>>(counts, dinv, N);
  int nb = (N + 1023) / 1024;
  k_scan1<<<nb, 1024, 0, stream>>>(counts, rowptr, bsums, N);
  k_scan2<<<1, 64, 0, stream>>>(bsums, nb);
  k_scan3<<<nb, 1024, 0, stream>>>(rowptr, bsums, N, E);
  k_scatter<<<(E + 255) / 256, 256, 0, stream>>>(ei, E, rowptr, cursor, csrc);

  // ---- fused weights (once) ----
  k_mmnaive<128><<<(128 * 128 + 255) / 256, 256, 0, stream>>>(W1, W2, wtmp);
  k_mmnaive<64><<<(128 * 64 + 255) / 256, 256, 0, stream>>>(wtmp, W3, wc);
  k_cvec<<<1, 128, 0, stream>>>(b1, b2, b3, W2, W3, c1, c2, c3);

  // ---- P0 = dinv * (X @ Wc), slice-major bf16 ----
  k_xw<<<(N + 63) / 64, 256, 0, stream>>>(X, wc, dinv, Hfull, N, W);

  // ---- per slice: 3 aggregation rounds (one node per wave) ----
  int gb = (N + 3) / 4;   // 4 waves (nodes) per 256-thread block
  for (int pp = 0; pp < SLICES; ++pp) {
    int c0 = pp * W;
    int pass0 = (pp == 0) ? 1 : 0;
    ushort* Hp = Hfull + (size_t)pp * N * W;
    k_agg<1><<<gb, 256, 0, stream>>>(Hp, S1, nullptr, rowptr, csrc, dinv,
                                     r1t, r1s, r2t, c1, c2, c3, N, W, wsh, c0, pass0);
    k_agg<2><<<gb, 256, 0, stream>>>(S1, Hp, nullptr, rowptr, csrc, dinv,
                                     r1t, r1s, r2t, c1, c2, c3, N, W, wsh, c0, pass0);
    k_agg<3><<<gb, 256, 0, stream>>>(Hp, nullptr, out, rowptr, csrc, dinv,
                                     r1t, r1s, r2t, c1, c2, c3, N, W, wsh, c0, 0);
  }
}

// Round 9
// 182.232 us; speedup vs baseline: 1.4833x; 1.4833x over previous
//
#include <hip/hip_runtime.h>

#define DIN 128
#define DHID 128
#define DOUT 64

__device__ __forceinline__ ushort f2bf(float f) {  // round-to-nearest-even
  unsigned u = __float_as_uint(f);
  return (ushort)((u + 0x7fffu + ((u >> 16) & 1u)) >> 16);
}

// ---------------- CSR build ----------------

__global__ void k_init(int* counts, int* cursor, int n) {
  int i = blockIdx.x * blockDim.x + threadIdx.x;
  if (i < n) { counts[i] = 0; cursor[i] = 0; }
}

__global__ void k_hist(const int* __restrict__ ei, int E, int* __restrict__ counts) {
  int e = blockIdx.x * blockDim.x + threadIdx.x;
  if (e < E) atomicAdd(&counts[__builtin_nontemporal_load(ei + E + e)], 1);
}

__global__ void k_dinv(const int* __restrict__ counts, float* __restrict__ dinv, int n) {
  int i = blockIdx.x * blockDim.x + threadIdx.x;
  if (i < n) dinv[i] = 1.0f / sqrtf((float)(counts[i] + 1));  // +1 self loop
}

__global__ __launch_bounds__(1024) void k_scan1(const int* __restrict__ counts,
                                                int* __restrict__ rowptr,
                                                int* __restrict__ bsums, int n) {
  __shared__ int s[1024];
  int tid = threadIdx.x;
  int idx = blockIdx.x * 1024 + tid;
  int v = (idx < n) ? counts[idx] : 0;
  s[tid] = v;
  __syncthreads();
  for (int off = 1; off < 1024; off <<= 1) {
    int t = (tid >= off) ? s[tid - off] : 0;
    __syncthreads();
    s[tid] += t;
    __syncthreads();
  }
  if (idx < n) rowptr[idx] = s[tid] - v;   // exclusive within block
  if (tid == 1023) bsums[blockIdx.x] = s[1023];
}

__global__ void k_scan2(int* bsums, int nb) {
  // one wave, nb <= 64 (N <= 65536). exclusive scan of block sums.
  int l = threadIdx.x;
  if (nb <= 64) {
    int v = (l < nb) ? bsums[l] : 0;
    int orig = v;
    for (int off = 1; off < 64; off <<= 1) {
      int t = __shfl_up(v, off);
      if (l >= off) v += t;
    }
    if (l < nb) bsums[l] = v - orig;
  } else if (l == 0) {
    int run = 0;
    for (int b = 0; b < nb; ++b) { int v = bsums[b]; bsums[b] = run; run += v; }
  }
}

__global__ __launch_bounds__(1024) void k_scan3(int* __restrict__ rowptr,
                                                const int* __restrict__ bsums, int n, int E) {
  int idx = blockIdx.x * 1024 + threadIdx.x;
  if (idx < n) rowptr[idx] += bsums[blockIdx.x];
  if (idx == 0) rowptr[n] = E;
}

__global__ void k_scatter(const int* __restrict__ ei, int E,
                          const int* __restrict__ rowptr, int* __restrict__ cursor,
                          ushort* __restrict__ csrc) {
  int e = blockIdx.x * blockDim.x + threadIdx.x;
  if (e >= E) return;
  int s = __builtin_nontemporal_load(ei + e);
  int d = __builtin_nontemporal_load(ei + E + e);
  int pos = rowptr[d] + atomicAdd(&cursor[d], 1);
  csrc[pos] = (ushort)s;            // N < 65536
}

// ---------------- tiny weight GEMMs ----------------

template <int NCOL>
__global__ void k_mmnaive(const float* __restrict__ A, const float* __restrict__ B,
                          float* __restrict__ C) {
  int t = blockIdx.x * blockDim.x + threadIdx.x;
  if (t >= 128 * NCOL) return;
  int i = t / NCOL, j = t % NCOL;
  float s = 0.f;
  for (int k = 0; k < 128; ++k) s = fmaf(A[i * 128 + k], B[k * NCOL + j], s);
  C[t] = s;
}

__global__ void k_cvec(const float* __restrict__ b1, const float* __restrict__ b2,
                       const float* __restrict__ b3, const float* __restrict__ W2,
                       const float* __restrict__ W3, float* __restrict__ c1,
                       float* __restrict__ c2, float* __restrict__ c3) {
  __shared__ float t1[DHID];
  int j = threadIdx.x;
  float s = 0.f;
  for (int k = 0; k < DHID; ++k) s = fmaf(b1[k], W2[k * DHID + j], s);
  t1[j] = s;
  __syncthreads();
  if (j < DOUT) {
    float a = 0.f, b = 0.f;
    for (int k = 0; k < DHID; ++k) {
      a = fmaf(t1[k], W3[k * DOUT + j], a);
      b = fmaf(b2[k], W3[k * DOUT + j], b);
    }
    c1[j] = a; c2[j] = b; c3[j] = b3[j];
  }
}

// ---------------- P0 = dinv * (X @ Wc), bf16 [N][64] ----------------

__global__ __launch_bounds__(256) void k_xw(const float* __restrict__ X,
                                            const float* __restrict__ Wc,
                                            const float* __restrict__ dinv,
                                            ushort* __restrict__ H, int n) {
  __shared__ float Xs[64][68];
  __shared__ float Ws[64][64];
  int t = threadIdx.x;
  int br = blockIdx.x * 64;
  int r4 = t >> 4, c4 = t & 15;
  float4 acc[4];
#pragma unroll
  for (int i = 0; i < 4; ++i) acc[i] = make_float4(0.f, 0.f, 0.f, 0.f);

  for (int chunk = 0; chunk < 2; ++chunk) {
    int k0 = chunk * 64;
    __syncthreads();
#pragma unroll
    for (int j = 0; j < 4; ++j) {
      int f4 = t + j * 256;
      int row = f4 >> 4, col4 = f4 & 15;
      int gr = br + row;
      float4 v = make_float4(0.f, 0.f, 0.f, 0.f);
      if (gr < n) v = *(const float4*)&X[(size_t)gr * DIN + k0 + col4 * 4];
      *(float4*)&Xs[row][col4 * 4] = v;
      float4 w = *(const float4*)&Wc[(size_t)(k0 + row) * DOUT + col4 * 4];
      *(float4*)&Ws[row][col4 * 4] = w;
    }
    __syncthreads();
#pragma unroll
    for (int kk = 0; kk < 16; ++kk) {
      float4 xv[4], wv[4];
#pragma unroll
      for (int i = 0; i < 4; ++i) xv[i] = *(const float4*)&Xs[r4 * 4 + i][kk * 4];
#pragma unroll
      for (int q = 0; q < 4; ++q) wv[q] = *(const float4*)&Ws[kk * 4 + q][c4 * 4];
#pragma unroll
      for (int i = 0; i < 4; ++i) {
        acc[i].x = fmaf(xv[i].x, wv[0].x, acc[i].x);
        acc[i].y = fmaf(xv[i].x, wv[0].y, acc[i].y);
        acc[i].z = fmaf(xv[i].x, wv[0].z, acc[i].z);
        acc[i].w = fmaf(xv[i].x, wv[0].w, acc[i].w);
        acc[i].x = fmaf(xv[i].y, wv[1].x, acc[i].x);
        acc[i].y = fmaf(xv[i].y, wv[1].y, acc[i].y);
        acc[i].z = fmaf(xv[i].y, wv[1].z, acc[i].z);
        acc[i].w = fmaf(xv[i].y, wv[1].w, acc[i].w);
        acc[i].x = fmaf(xv[i].z, wv[2].x, acc[i].x);
        acc[i].y = fmaf(xv[i].z, wv[2].y, acc[i].y);
        acc[i].z = fmaf(xv[i].z, wv[2].z, acc[i].z);
        acc[i].w = fmaf(xv[i].z, wv[2].w, acc[i].w);
        acc[i].x = fmaf(xv[i].w, wv[3].x, acc[i].x);
        acc[i].y = fmaf(xv[i].w, wv[3].y, acc[i].y);
        acc[i].z = fmaf(xv[i].w, wv[3].z, acc[i].z);
        acc[i].w = fmaf(xv[i].w, wv[3].w, acc[i].w);
      }
    }
  }
#pragma unroll
  for (int i = 0; i < 4; ++i) {
    int gr = br + r4 * 4 + i;
    if (gr < n) {
      float dv = dinv[gr];
      ushort4 hv;
      hv.x = f2bf(acc[i].x * dv); hv.y = f2bf(acc[i].y * dv);
      hv.z = f2bf(acc[i].z * dv); hv.w = f2bf(acc[i].w * dv);
      *(ushort4*)&H[(size_t)gr * DOUT + c4 * 4] = hv;
    }
  }
}

// ---------------- aggregation: one wave per node, 2 edges per gather inst ----
// Lanes split into 2 halves; lane = (half, fl). Each lane loads a uint
// (feats 2fl, 2fl+1 packed bf16) of its half's edge. Combine via shfl_xor(32).
// input P (= dinv * H). T[v] = P[v] + sum_in P[s].
// rounds 1,2 write Pnext = dinv^2*T (bf16); round 3 writes di*T + rank-1 bias.

template <int ROUND>
__global__ __launch_bounds__(256) void k_agg(const uint* __restrict__ in,
                                             uint* __restrict__ out16,
                                             float* __restrict__ out32,
                                             const int* __restrict__ rowptr,
                                             const ushort* __restrict__ csrc,
                                             const float* __restrict__ dinv,
                                             float* __restrict__ r1t, float* __restrict__ r1s,
                                             float* __restrict__ r2t,
                                             const float* __restrict__ c1,
                                             const float* __restrict__ c2,
                                             const float* __restrict__ c3, int n) {
  int node = (blockIdx.x * blockDim.x + threadIdx.x) >> 6;
  if (node >= n) return;
  int lane = threadIdx.x & 63;
  int half = lane >> 5;                  // edge sub-group (0/1)
  int fl   = lane & 31;                  // feature-pair index
  int beg = rowptr[node], end = rowptr[node + 1];
  float di = dinv[node];
  float ax0 = 0.f, ay0 = 0.f, ax1 = 0.f, ay1 = 0.f;
  float ax2 = 0.f, ay2 = 0.f, ax3 = 0.f, ay3 = 0.f;
  float racc = 0.f;
  int e = beg + half;
  for (; e + 6 < end; e += 8) {          // 4 edges per half in flight (8/wave)
    int s0 = csrc[e];
    int s1 = csrc[e + 2];
    int s2 = csrc[e + 4];
    int s3 = csrc[e + 6];
    uint u0 = in[(size_t)s0 * 32 + fl];
    uint u1 = in[(size_t)s1 * 32 + fl];
    uint u2 = in[(size_t)s2 * 32 + fl];
    uint u3 = in[(size_t)s3 * 32 + fl];
    ax0 += __uint_as_float(u0 << 16); ay0 += __uint_as_float(u0 & 0xffff0000u);
    ax1 += __uint_as_float(u1 << 16); ay1 += __uint_as_float(u1 & 0xffff0000u);
    ax2 += __uint_as_float(u2 << 16); ay2 += __uint_as_float(u2 & 0xffff0000u);
    ax3 += __uint_as_float(u3 << 16); ay3 += __uint_as_float(u3 & 0xffff0000u);
    if (ROUND == 1) racc += (dinv[s0] + dinv[s1]) + (dinv[s2] + dinv[s3]);
    if (ROUND == 2) racc += (r1s[s0] + r1s[s1]) + (r1s[s2] + r1s[s3]);
  }
  for (; e < end; e += 2) {
    int s = csrc[e];
    uint u = in[(size_t)s * 32 + fl];
    ax0 += __uint_as_float(u << 16); ay0 += __uint_as_float(u & 0xffff0000u);
    if (ROUND == 1) racc += dinv[s];
    if (ROUND == 2) racc += r1s[s];
  }
  float ax = (ax0 + ax1) + (ax2 + ax3);
  float ay = (ay0 + ay1) + (ay2 + ay3);
  ax += __shfl_xor(ax, 32);
  ay += __shfl_xor(ay, 32);
  if (ROUND != 3) racc += __shfl_xor(racc, 32);
  uint us = in[(size_t)node * 32 + fl];                 // self P[v]
  float Tx = ax + __uint_as_float(us << 16);
  float Ty = ay + __uint_as_float(us & 0xffff0000u);
  float d2 = di * di;
  if (ROUND == 1) {
    racc += di;                                         // self p0 = dinv_v
    if (lane == 0) { r1t[node] = di * racc; r1s[node] = d2 * racc; }
  }
  if (ROUND == 2) {
    racc += r1s[node];                                  // self term
    if (lane == 0) r2t[node] = di * racc;
  }
  if (half == 0) {
    if (ROUND == 3) {
      int cf = 2 * fl;
      float vx = fmaf(r1t[node], c2[cf], c3[cf]);
      vx = fmaf(r2t[node], c1[cf], vx);
      float vy = fmaf(r1t[node], c2[cf + 1], c3[cf + 1]);
      vy = fmaf(r2t[node], c1[cf + 1], vy);
      float2 o;
      o.x = fmaf(di, Tx, vx);
      o.y = fmaf(di, Ty, vy);
      *(float2*)&out32[(size_t)node * DOUT + cf] = o;
    } else {
      uint pk = (uint)f2bf(d2 * Tx) | ((uint)f2bf(d2 * Ty) << 16);
      out16[(size_t)node * 32 + fl] = pk;
    }
  }
}

// ---------------- launch ----------------

extern "C" void kernel_launch(void* const* d_in, const int* in_sizes, int n_in,
                              void* d_out, int out_size, void* d_ws, size_t ws_size,
                              hipStream_t stream) {
  const float* X  = (const float*)d_in[0];
  const int*   ei = (const int*)d_in[1];
  const float* W1 = (const float*)d_in[2];
  const float* b1 = (const float*)d_in[3];
  const float* W2 = (const float*)d_in[4];
  const float* b2 = (const float*)d_in[5];
  const float* W3 = (const float*)d_in[6];
  const float* b3 = (const float*)d_in[7];
  const int N = in_sizes[0] / DIN;
  const int E = in_sizes[1] / 2;
  float* out = (float*)d_out;

  auto AL = [](size_t x) -> size_t { return (x + 255) & ~(size_t)255; };

  char* p = (char*)d_ws;
  auto alloc = [&](size_t nbytes) -> void* {
    void* r = (void*)p;
    p += AL(nbytes);
    return r;
  };
  // total ~14.9 MB (csrc as ushort): under the proven-good 15.7 MB footprint
  int*    rowptr = (int*)alloc((size_t)(N + 1) * 4);
  int*    bsums  = (int*)alloc(256 * 4);
  float*  dinv   = (float*)alloc((size_t)N * 4);
  ushort* csrc   = (ushort*)alloc((size_t)E * 2);
  int*    counts = (int*)alloc((size_t)N * 4);   // aliased -> r1t
  int*    cursor = (int*)alloc((size_t)N * 4);   // aliased -> r1s
  float*  r2t    = (float*)alloc((size_t)N * 4);
  float*  wtmp   = (float*)alloc((size_t)DIN * DHID * 4);
  float*  wc     = (float*)alloc((size_t)DIN * DOUT * 4);
  float*  c1     = (float*)alloc(DOUT * 4);
  float*  c2     = (float*)alloc(DOUT * 4);
  float*  c3     = (float*)alloc(DOUT * 4);
  uint*   H1     = (uint*)alloc((size_t)N * 32 * 4);  // [N][32] uints = bf16 x64
  uint*   H2     = (uint*)alloc((size_t)N * 32 * 4);
  float*  r1t    = (float*)counts;
  float*  r1s    = (float*)cursor;

  // ---- CSR build (once) ----
  k_init<<<(N + 255) / 256, 256, 0, stream>>>(counts, cursor, N);
  k_hist<<<(E + 255) / 256, 256, 0, stream>>>(ei, E, counts);
  k_dinv<<<(N + 255) / 256, 256, 0, stream>>>(counts, dinv, N);
  int nb = (N + 1023) / 1024;
  k_scan1<<<nb, 1024, 0, stream>>>(counts, rowptr, bsums, N);
  k_scan2<<<1, 64, 0, stream>>>(bsums, nb);
  k_scan3<<<nb, 1024, 0, stream>>>(rowptr, bsums, N, E);
  k_scatter<<<(E + 255) / 256, 256, 0, stream>>>(ei, E, rowptr, cursor, csrc);

  // ---- fused weights (once) ----
  k_mmnaive<128><<<(128 * 128 + 255) / 256, 256, 0, stream>>>(W1, W2, wtmp);
  k_mmnaive<64><<<(128 * 64 + 255) / 256, 256, 0, stream>>>(wtmp, W3, wc);
  k_cvec<<<1, 128, 0, stream>>>(b1, b2, b3, W2, W3, c1, c2, c3);

  // ---- P0 = dinv * (X @ Wc), bf16 ----
  k_xw<<<(N + 63) / 64, 256, 0, stream>>>(X, wc, dinv, (ushort*)H1, N);

  // ---- 3 aggregation rounds, one wave per node ----
  int gb = (N + 3) / 4;   // 4 waves (nodes) per 256-thread block
  k_agg<1><<<gb, 256, 0, stream>>>(H1, H2, nullptr, rowptr, csrc, dinv,
                                   r1t, r1s, r2t, c1, c2, c3, N);
  k_agg<2><<<gb, 256, 0, stream>>>(H2, H1, nullptr, rowptr, csrc, dinv,
                                   r1t, r1s, r2t, c1, c2, c3, N);
  k_agg<3><<<gb, 256, 0, stream>>>(H1, nullptr, out, rowptr, csrc, dinv,
                                   r1t, r1s, r2t, c1, c2, c3, N);
}